// Round 1
// baseline (120.352 us; speedup 1.0000x reference)
//
#include <hip/hip_runtime.h>

// FlowLenia step, SX=SY=256, C=3, K=15.
// Pipeline:
//   K1 row-FFT of A (3 planes)            -> RF   [c][x][y] complex
//   K2 col-FFT + fK mul + inv col-FFT     -> T2   [k][x][y] complex
//   K3 inv row-FFT + growth*P + collapse  -> Ucol [c][x][y] real
//   K4 Sobel flow                         -> F    [x][y][2][3] real
//   K5 5x5 reintegration + softmax mix    -> d_out (newA | newP)

#define SXY 256
#define XY  65536
#define NC  3
#define NK  15

__device__ __forceinline__ float2 cmul(float2 a, float2 b) {
  return make_float2(a.x * b.x - a.y * b.y, a.x * b.y + a.y * b.x);
}

// 256-pt Stockham radix-4 FFT, 64 threads, LDS ping-pong. Result lands in b0.
// sign = -1 forward, +1 inverse (unnormalized). Natural order in/out.
__device__ __forceinline__ void fft256_lds(float2* b0, float2* b1, int t, float sign) {
  float2* src = b0;
  float2* dst = b1;
#pragma unroll
  for (int stage = 0; stage < 4; ++stage) {
    __syncthreads();  // covers caller's fill and previous stage's writes
    const int Ns = 1 << (2 * stage);
    float2 v0 = src[t];
    float2 v1 = src[t + 64];
    float2 v2 = src[t + 128];
    float2 v3 = src[t + 192];
    const int jm = t & (Ns - 1);
    float ang = sign * 6.283185307179586f * (float)jm / (float)(Ns * 4);
    float sn, cs;
    __sincosf(ang, &sn, &cs);
    float2 w1 = make_float2(cs, sn);
    float2 w2 = cmul(w1, w1);
    float2 w3 = cmul(w2, w1);
    v1 = cmul(v1, w1);
    v2 = cmul(v2, w2);
    v3 = cmul(v3, w3);
    float2 a0 = make_float2(v0.x + v2.x, v0.y + v2.y);
    float2 a1 = make_float2(v0.x - v2.x, v0.y - v2.y);
    float2 a2 = make_float2(v1.x + v3.x, v1.y + v3.y);
    float2 a3 = make_float2(v1.x - v3.x, v1.y - v3.y);
    float2 ia3 = make_float2(-sign * a3.y, sign * a3.x);  // (sign*i)*a3
    const int idxD = ((t >> (2 * stage)) << (2 * stage)) * 4 + jm;  // (t/Ns)*4Ns + jm
    dst[idxD]          = make_float2(a0.x + a2.x, a0.y + a2.y);
    dst[idxD + Ns]     = make_float2(a1.x + ia3.x, a1.y + ia3.y);
    dst[idxD + 2 * Ns] = make_float2(a0.x - a2.x, a0.y - a2.y);
    dst[idxD + 3 * Ns] = make_float2(a1.x - ia3.x, a1.y - ia3.y);
    float2* tmp = src; src = dst; dst = tmp;
  }
  __syncthreads();
}

// K1: forward FFT along y for each (channel, row). grid = 3*256 blocks x 64.
__global__ __launch_bounds__(64) void k_rowfft(const float* __restrict__ A,
                                               float2* __restrict__ RF) {
  __shared__ float2 b0[256], b1[256];
  const int t = threadIdx.x;
  const int x = blockIdx.x & 255;
  const int c = blockIdx.x >> 8;
#pragma unroll
  for (int r = 0; r < 4; ++r) {
    int y = t + 64 * r;
    b0[y] = make_float2(A[(x * 256 + y) * NC + c], 0.0f);
  }
  fft256_lds(b0, b1, t, -1.0f);
#pragma unroll
  for (int r = 0; r < 4; ++r) {
    int y = t + 64 * r;
    RF[(c * 256 + x) * 256 + y] = b0[y];
  }
}

// K2: forward FFT along x (one column per block), multiply by fK, inverse FFT
// along x, for the 5 kernels of this channel. grid = 3*256 blocks x 64.
__global__ __launch_bounds__(64) void k_colfft(const float* __restrict__ fKr,
                                               const float* __restrict__ fKi,
                                               const float2* __restrict__ RF,
                                               float2* __restrict__ T2) {
  __shared__ float2 b0[256], b1[256];
  const int t = threadIdx.x;
  const int y = blockIdx.x & 255;
  const int c = blockIdx.x >> 8;
#pragma unroll
  for (int r = 0; r < 4; ++r) {
    int x = t + 64 * r;
    b0[x] = RF[(c * 256 + x) * 256 + y];
  }
  fft256_lds(b0, b1, t, -1.0f);
  // keep this thread's spectrum elements in registers (it wrote/reads x = t+64r)
  float2 fa[4];
#pragma unroll
  for (int r = 0; r < 4; ++r) fa[r] = b0[t + 64 * r];
  for (int j = 0; j < 5; ++j) {
    const int k = c + 3 * j;
#pragma unroll
    for (int r = 0; r < 4; ++r) {
      int x = t + 64 * r;
      float2 Kv = make_float2(fKr[(x * 256 + y) * NK + k], fKi[(x * 256 + y) * NK + k]);
      b0[x] = cmul(Kv, fa[r]);
    }
    fft256_lds(b0, b1, t, 1.0f);
#pragma unroll
    for (int r = 0; r < 4; ++r) {
      int x = t + 64 * r;
      T2[(k * 256 + x) * 256 + y] = b0[x];
    }
  }
}

// K3: inverse FFT along y, growth(U,m,s)*P, collapse 5 kernels -> Ucol channel.
// grid = 3*256 blocks x 64.
__global__ __launch_bounds__(64) void k_irowfft_growth(const float2* __restrict__ T2,
                                                       const float* __restrict__ P,
                                                       const float* __restrict__ m,
                                                       const float* __restrict__ s,
                                                       float* __restrict__ Ucol) {
  __shared__ float2 b0[256], b1[256];
  const int t = threadIdx.x;
  const int x = blockIdx.x & 255;
  const int c = blockIdx.x >> 8;
  float acc[4] = {0.f, 0.f, 0.f, 0.f};
  for (int j = 0; j < 5; ++j) {
    const int k = c + 3 * j;
    const float mk = m[k];
    const float sk = s[k];
    const float inv2s2 = 0.5f / (sk * sk);
#pragma unroll
    for (int r = 0; r < 4; ++r) {
      int y = t + 64 * r;
      b0[y] = T2[(k * 256 + x) * 256 + y];
    }
    fft256_lds(b0, b1, t, 1.0f);
#pragma unroll
    for (int q = 0; q < 4; ++q) {
      int y = t + 64 * q;
      float U = b0[y].x * (1.0f / 65536.0f);
      float d = U - mk;
      float g = 2.0f * __expf(-d * d * inv2s2) - 1.0f;
      acc[q] += g * P[(x * 256 + y) * NK + k];
    }
  }
#pragma unroll
  for (int q = 0; q < 4; ++q) {
    int y = t + 64 * q;
    Ucol[(c * 256 + x) * 256 + y] = acc[q];
  }
}

// K4: Sobel flow. F = clip(sobel(Ucol)*(1-alpha) - sobel(Asum)*alpha, +-MA).
// grid = 256 blocks x 256.
__global__ __launch_bounds__(256) void k_flow(const float* __restrict__ A,
                                              const float* __restrict__ Ucol,
                                              float* __restrict__ F) {
  const int idx = blockIdx.x * 256 + threadIdx.x;
  const int x = idx >> 8;
  const int y = idx & 255;
  const float MA = 4.35f;

  float u[3][3][3];
  float asum[3][3];
#pragma unroll
  for (int di = -1; di <= 1; ++di) {
#pragma unroll
    for (int dj = -1; dj <= 1; ++dj) {
      int xi = x + di, yj = y + dj;
      bool inb = ((unsigned)xi < 256u) && ((unsigned)yj < 256u);
      float a0 = 0.f, a1 = 0.f, a2 = 0.f, as = 0.f;
      if (inb) {
        int b = xi * 256 + yj;
        a0 = Ucol[0 * XY + b];
        a1 = Ucol[1 * XY + b];
        a2 = Ucol[2 * XY + b];
        const float* ap = A + b * NC;
        as = ap[0] + ap[1] + ap[2];
      }
      u[0][di + 1][dj + 1] = a0;
      u[1][di + 1][dj + 1] = a1;
      u[2][di + 1][dj + 1] = a2;
      asum[di + 1][dj + 1] = as;
    }
  }
  // d/dx (axis0) and d/dy (axis1) sobel (true-convolution semantics)
  float cg0 = (asum[2][0] + 2.f * asum[2][1] + asum[2][2]) -
              (asum[0][0] + 2.f * asum[0][1] + asum[0][2]);
  float cg1 = (asum[0][2] + 2.f * asum[1][2] + asum[2][2]) -
              (asum[0][0] + 2.f * asum[1][0] + asum[2][0]);
  const int b = x * 256 + y;
#pragma unroll
  for (int c = 0; c < NC; ++c) {
    float f0 = (u[c][2][0] + 2.f * u[c][2][1] + u[c][2][2]) -
               (u[c][0][0] + 2.f * u[c][0][1] + u[c][0][2]);
    float f1 = (u[c][0][2] + 2.f * u[c][1][2] + u[c][2][2]) -
               (u[c][0][0] + 2.f * u[c][1][0] + u[c][2][0]);
    float ah = A[b * NC + c] * 0.5f;
    float al = fminf(ah * ah, 1.0f);
    f0 = fminf(fmaxf(f0 * (1.f - al) - cg0 * al, -MA), MA);
    f1 = fminf(fmaxf(f1 * (1.f - al) - cg1 * al, -MA), MA);
    F[(b * 2 + 0) * NC + c] = f0;
    F[(b * 2 + 1) * NC + c] = f1;
  }
}

// K5: reintegration. For each target cell gather 5x5 sources (shifts beyond
// |2| have exactly zero area since |DT*F| <= 0.87 and box halfwidth = 1.15).
// grid = 256 blocks x 256.
__global__ __launch_bounds__(256) void k_reint(const float* __restrict__ A,
                                               const float* __restrict__ P,
                                               const float* __restrict__ F,
                                               float* __restrict__ outA,
                                               float* __restrict__ outP) {
  const int idx = blockIdx.x * 256 + threadIdx.x;
  const int x = idx >> 8;
  const int y = idx & 255;
  const float SIGMA = 0.65f;
  const float INV4S2 = 1.0f / (4.0f * 0.65f * 0.65f);
  const float DT = 0.2f;
  const float px = x + 0.5f;
  const float py = y + 0.5f;

  float accA[3] = {0.f, 0.f, 0.f};
  float accP[15];
#pragma unroll
  for (int k = 0; k < NK; ++k) accP[k] = 0.f;
  float esum = 0.f;

  for (int dx = -2; dx <= 2; ++dx) {
    for (int dy = -2; dy <= 2; ++dy) {
      const int sx = (x - dx) & 255;
      const int sy = (y - dy) & 255;
      const int sb = sx * 256 + sy;
      const float spx = sx + 0.5f;
      const float spy = sy + 0.5f;
      float sumnA = 0.f;
      float nAc[3];
#pragma unroll
      for (int c = 0; c < NC; ++c) {
        float f0 = F[(sb * 2 + 0) * NC + c];
        float f1 = F[(sb * 2 + 1) * NC + c];
        float mu0 = fminf(fmaxf(spx + DT * f0, SIGMA), 256.f - SIGMA);
        float mu1 = fminf(fmaxf(spy + DT * f1, SIGMA), 256.f - SIGMA);
        float sz0 = 0.5f - fabsf(px - mu0) + SIGMA;
        float sz1 = 0.5f - fabsf(py - mu1) + SIGMA;
        sz0 = fminf(fmaxf(sz0, 0.f), 1.f);
        sz1 = fminf(fmaxf(sz1, 0.f), 1.f);
        float area = sz0 * sz1 * INV4S2;
        float na = A[sb * NC + c] * area;
        nAc[c] = na;
        sumnA += na;
      }
      float e = __expf(sumnA) - 1.0f;
      accA[0] += nAc[0];
      accA[1] += nAc[1];
      accA[2] += nAc[2];
      esum += e;
      const float* pp = P + sb * NK;
#pragma unroll
      for (int k = 0; k < NK; ++k) accP[k] += pp[k] * e;
    }
  }
  const int b = x * 256 + y;
#pragma unroll
  for (int c = 0; c < NC; ++c) outA[b * NC + c] = accA[c];
  const float inv = 1.0f / (esum + 1e-10f);
#pragma unroll
  for (int k = 0; k < NK; ++k) outP[b * NK + k] = accP[k] * inv;
}

extern "C" void kernel_launch(void* const* d_in, const int* in_sizes, int n_in,
                              void* d_out, int out_size, void* d_ws, size_t ws_size,
                              hipStream_t stream) {
  const float* A   = (const float*)d_in[0];
  const float* P   = (const float*)d_in[1];
  const float* fKr = (const float*)d_in[2];
  const float* fKi = (const float*)d_in[3];
  const float* m   = (const float*)d_in[4];
  const float* s   = (const float*)d_in[5];

  float* ws = (float*)d_ws;
  float2* RF   = (float2*)ws;            // 3 * 65536 complex
  float2* T2   = RF + NC * XY;           // 15 * 65536 complex
  float*  Ucol = (float*)(T2 + NK * XY); // 3 * 65536 float
  float*  F    = Ucol + NC * XY;         // 65536 * 2 * 3 float

  float* outA = (float*)d_out;
  float* outP = outA + NC * XY;

  k_rowfft<<<NC * 256, 64, 0, stream>>>(A, RF);
  k_colfft<<<NC * 256, 64, 0, stream>>>(fKr, fKi, RF, T2);
  k_irowfft_growth<<<NC * 256, 64, 0, stream>>>(T2, P, m, s, Ucol);
  k_flow<<<256, 256, 0, stream>>>(A, Ucol, F);
  k_reint<<<256, 256, 0, stream>>>(A, P, F, outA, outP);
}

// Round 3
// 107.334 us; speedup vs baseline: 1.1213x; 1.1213x over previous
//
#include <hip/hip_runtime.h>

// FlowLenia step, SX=SY=256, C=3, K=15.
// Pipeline:
//   K1 row-FFT of A (3 planes)                      -> RF [c][x][y] complex
//   K2 fwd col-FFT + fK mul + inv col-FFT per k     -> T2 [k][x][y] complex
//      (8 columns/block, 8 waves, line-granular global I/O, LDS transpose)
//   K3 inv row-FFT + growth*P + collapse (5 waves)  -> Ucol [c][x][y] real
//   K4 Sobel flow                                   -> F    [x][y][2][3] real
//   K5 5x5 reintegration + softmax mix              -> d_out (newA | newP)

#define XY  65536
#define NC  3
#define NK  15
#define WPAD 260   // per-wave LDS buffer stride (float2), pad to spread banks

__device__ __forceinline__ float2 cmul(float2 a, float2 b) {
  return make_float2(a.x * b.x - a.y * b.y, a.x * b.y + a.y * b.x);
}

// 256-pt Stockham radix-4 FFT on a wave-private 256-float2 LDS buffer pair.
// t = lane (0..63). sign = -1 fwd, +1 inv (unnormalized). Result lands in b0.
// Uses __syncthreads() as the stage barrier; all waves in the block must call
// this together (identical control flow).
__device__ __forceinline__ void fft256_lds(float2* b0, float2* b1, int t, float sign) {
  float2* src = b0;
  float2* dst = b1;
#pragma unroll
  for (int stage = 0; stage < 4; ++stage) {
    __syncthreads();  // covers caller's fill and previous stage's writes
    const int Ns = 1 << (2 * stage);
    float2 v0 = src[t];
    float2 v1 = src[t + 64];
    float2 v2 = src[t + 128];
    float2 v3 = src[t + 192];
    const int jm = t & (Ns - 1);
    float ang = sign * 6.283185307179586f * (float)jm / (float)(Ns * 4);
    float sn, cs;
    __sincosf(ang, &sn, &cs);
    float2 w1 = make_float2(cs, sn);
    float2 w2 = cmul(w1, w1);
    float2 w3 = cmul(w2, w1);
    v1 = cmul(v1, w1);
    v2 = cmul(v2, w2);
    v3 = cmul(v3, w3);
    float2 a0 = make_float2(v0.x + v2.x, v0.y + v2.y);
    float2 a1 = make_float2(v0.x - v2.x, v0.y - v2.y);
    float2 a2 = make_float2(v1.x + v3.x, v1.y + v3.y);
    float2 a3 = make_float2(v1.x - v3.x, v1.y - v3.y);
    float2 ia3 = make_float2(-sign * a3.y, sign * a3.x);  // (sign*i)*a3
    const int idxD = ((t >> (2 * stage)) << (2 * stage)) * 4 + jm;  // (t/Ns)*4Ns + jm
    dst[idxD]          = make_float2(a0.x + a2.x, a0.y + a2.y);
    dst[idxD + Ns]     = make_float2(a1.x + ia3.x, a1.y + ia3.y);
    dst[idxD + 2 * Ns] = make_float2(a0.x - a2.x, a0.y - a2.y);
    dst[idxD + 3 * Ns] = make_float2(a1.x - ia3.x, a1.y - ia3.y);
    float2* tmp = src; src = dst; dst = tmp;
  }
  __syncthreads();
}

// K1: forward FFT along y for each (channel, row). grid = 3*256 blocks x 64.
__global__ __launch_bounds__(64) void k_rowfft(const float* __restrict__ A,
                                               float2* __restrict__ RF) {
  __shared__ float2 b0[256], b1[256];
  const int t = threadIdx.x;
  const int x = blockIdx.x & 255;
  const int c = blockIdx.x >> 8;
#pragma unroll
  for (int r = 0; r < 4; ++r) {
    int y = t + 64 * r;
    b0[y] = make_float2(A[(x * 256 + y) * NC + c], 0.0f);
  }
  fft256_lds(b0, b1, t, -1.0f);
#pragma unroll
  for (int r = 0; r < 4; ++r) {
    int y = t + 64 * r;
    RF[(c * 256 + x) * 256 + y] = b0[y];
  }
}

// K2: per (k, 8-column tile): fwd col FFT (redundant across the 5 k's of a
// channel -- compute is free), fK multiply, inverse col FFT.
// grid = 15*32 blocks x 512 (8 waves; wave w owns column y0+w).
// Tile is 256 rows x 8 float2 cols = 256 lines x 4 float4 chunks = 1024
// chunk-transfers -> each of the 512 threads moves TWO chunks (r loop).
__global__ __launch_bounds__(512, 1) void k_colfft(const float* __restrict__ fKr,
                                                   const float* __restrict__ fKi,
                                                   const float2* __restrict__ RF,
                                                   float2* __restrict__ T2) {
  __shared__ float2 lds0[8 * WPAD];
  __shared__ float2 lds1[8 * WPAD];
  const int tid = threadIdx.x;
  const int k = blockIdx.x >> 5;
  const int y0 = (blockIdx.x & 31) << 3;
  const int c = k % 3;

  // Tile load: chunk q (16B) of row x holds columns y0+2q, y0+2q+1.
  {
    const int q = tid & 3;
#pragma unroll
    for (int r = 0; r < 2; ++r) {
      const int x = (tid >> 2) + (r << 7);
      const float4* src = (const float4*)(RF + (c * XY + x * 256 + y0));
      float4 v = src[q];
      lds0[(2 * q) * WPAD + x]     = make_float2(v.x, v.y);
      lds0[(2 * q + 1) * WPAD + x] = make_float2(v.z, v.w);
    }
  }

  const int w = tid >> 6, lane = tid & 63;
  float2* b0 = lds0 + w * WPAD;
  float2* b1 = lds1 + w * WPAD;
  fft256_lds(b0, b1, lane, -1.0f);  // leading barrier covers tile fill

  const int y = y0 + w;
  float2 fa[4];
#pragma unroll
  for (int r = 0; r < 4; ++r) fa[r] = b0[lane + 64 * r];
#pragma unroll
  for (int r = 0; r < 4; ++r) {
    const int x = lane + 64 * r;
    const int fi = (x * 256 + y) * NK + k;
    float2 Kv = make_float2(fKr[fi], fKi[fi]);
    b0[x] = cmul(Kv, fa[r]);
  }
  fft256_lds(b0, b1, lane, 1.0f);  // trailing barrier makes lds0 block-visible

  // Tile store: mirror of the load.
  {
    const int q = tid & 3;
#pragma unroll
    for (int r = 0; r < 2; ++r) {
      const int x = (tid >> 2) + (r << 7);
      float2 v0 = lds0[(2 * q) * WPAD + x];
      float2 v1 = lds0[(2 * q + 1) * WPAD + x];
      float4* dst = (float4*)(T2 + (k * XY + x * 256 + y0));
      dst[q] = make_float4(v0.x, v0.y, v1.x, v1.y);
    }
  }
}

// K3: per (c, x): 5 waves, wave j handles k=c+3j: inverse row FFT (contiguous
// T2 reads), growth(U)*P, then cross-wave collapse -> Ucol channel.
// grid = 3*256 blocks x 320.
__global__ __launch_bounds__(320, 1) void k_irowfft_growth(const float2* __restrict__ T2,
                                                           const float* __restrict__ P,
                                                           const float* __restrict__ m,
                                                           const float* __restrict__ s,
                                                           float* __restrict__ Ucol) {
  __shared__ float2 lds0[5 * WPAD];
  __shared__ float2 lds1[5 * WPAD];
  __shared__ float accs[5 * WPAD];
  const int tid = threadIdx.x;
  const int x = blockIdx.x & 255;
  const int c = blockIdx.x >> 8;
  const int j = tid >> 6, lane = tid & 63;
  const int k = c + 3 * j;

  float2* b0 = lds0 + j * WPAD;
  float2* b1 = lds1 + j * WPAD;
  const float2* src = T2 + (k * XY + x * 256);
#pragma unroll
  for (int r = 0; r < 4; ++r) {
    int y = lane + 64 * r;
    b0[y] = src[y];
  }
  fft256_lds(b0, b1, lane, 1.0f);

  const float mk = m[k];
  const float sk = s[k];
  const float inv2s2 = 0.5f / (sk * sk);
#pragma unroll
  for (int r = 0; r < 4; ++r) {
    int y = lane + 64 * r;
    float U = b0[y].x * (1.0f / 65536.0f);
    float d = U - mk;
    float g = 2.0f * __expf(-d * d * inv2s2) - 1.0f;
    accs[j * WPAD + y] = g * P[(x * 256 + y) * NK + k];
  }
  __syncthreads();
  if (tid < 256) {
    float sum = 0.f;
#pragma unroll
    for (int j2 = 0; j2 < 5; ++j2) sum += accs[j2 * WPAD + tid];
    Ucol[c * XY + x * 256 + tid] = sum;
  }
}

// K4: Sobel flow. F = clip(sobel(Ucol)*(1-alpha) - sobel(Asum)*alpha, +-MA).
// grid = 256 blocks x 256.
__global__ __launch_bounds__(256) void k_flow(const float* __restrict__ A,
                                              const float* __restrict__ Ucol,
                                              float* __restrict__ F) {
  const int idx = blockIdx.x * 256 + threadIdx.x;
  const int x = idx >> 8;
  const int y = idx & 255;
  const float MA = 4.35f;

  float u[3][3][3];
  float asum[3][3];
#pragma unroll
  for (int di = -1; di <= 1; ++di) {
#pragma unroll
    for (int dj = -1; dj <= 1; ++dj) {
      int xi = x + di, yj = y + dj;
      bool inb = ((unsigned)xi < 256u) && ((unsigned)yj < 256u);
      float a0 = 0.f, a1 = 0.f, a2 = 0.f, as = 0.f;
      if (inb) {
        int b = xi * 256 + yj;
        a0 = Ucol[0 * XY + b];
        a1 = Ucol[1 * XY + b];
        a2 = Ucol[2 * XY + b];
        const float* ap = A + b * NC;
        as = ap[0] + ap[1] + ap[2];
      }
      u[0][di + 1][dj + 1] = a0;
      u[1][di + 1][dj + 1] = a1;
      u[2][di + 1][dj + 1] = a2;
      asum[di + 1][dj + 1] = as;
    }
  }
  float cg0 = (asum[2][0] + 2.f * asum[2][1] + asum[2][2]) -
              (asum[0][0] + 2.f * asum[0][1] + asum[0][2]);
  float cg1 = (asum[0][2] + 2.f * asum[1][2] + asum[2][2]) -
              (asum[0][0] + 2.f * asum[1][0] + asum[2][0]);
  const int b = x * 256 + y;
#pragma unroll
  for (int c = 0; c < NC; ++c) {
    float f0 = (u[c][2][0] + 2.f * u[c][2][1] + u[c][2][2]) -
               (u[c][0][0] + 2.f * u[c][0][1] + u[c][0][2]);
    float f1 = (u[c][0][2] + 2.f * u[c][1][2] + u[c][2][2]) -
               (u[c][0][0] + 2.f * u[c][1][0] + u[c][2][0]);
    float ah = A[b * NC + c] * 0.5f;
    float al = fminf(ah * ah, 1.0f);
    f0 = fminf(fmaxf(f0 * (1.f - al) - cg0 * al, -MA), MA);
    f1 = fminf(fmaxf(f1 * (1.f - al) - cg1 * al, -MA), MA);
    F[(b * 2 + 0) * NC + c] = f0;
    F[(b * 2 + 1) * NC + c] = f1;
  }
}

// K5: reintegration. 5x5 gather is exact: |DT*F| <= 0.87 and box halfwidth
// 0.5+SIGMA = 1.15, so |shift| >= 3 gives area == 0 -> exp(0)-1 == 0.
// grid = 256 blocks x 256.
__global__ __launch_bounds__(256) void k_reint(const float* __restrict__ A,
                                               const float* __restrict__ P,
                                               const float* __restrict__ F,
                                               float* __restrict__ outA,
                                               float* __restrict__ outP) {
  const int idx = blockIdx.x * 256 + threadIdx.x;
  const int x = idx >> 8;
  const int y = idx & 255;
  const float SIGMA = 0.65f;
  const float INV4S2 = 1.0f / (4.0f * 0.65f * 0.65f);
  const float DT = 0.2f;
  const float px = x + 0.5f;
  const float py = y + 0.5f;

  float accA[3] = {0.f, 0.f, 0.f};
  float accP[15];
#pragma unroll
  for (int k = 0; k < NK; ++k) accP[k] = 0.f;
  float esum = 0.f;

  for (int dx = -2; dx <= 2; ++dx) {
    for (int dy = -2; dy <= 2; ++dy) {
      const int sx = (x - dx) & 255;
      const int sy = (y - dy) & 255;
      const int sb = sx * 256 + sy;
      const float spx = sx + 0.5f;
      const float spy = sy + 0.5f;
      float sumnA = 0.f;
      float nAc[3];
#pragma unroll
      for (int c = 0; c < NC; ++c) {
        float f0 = F[(sb * 2 + 0) * NC + c];
        float f1 = F[(sb * 2 + 1) * NC + c];
        float mu0 = fminf(fmaxf(spx + DT * f0, SIGMA), 256.f - SIGMA);
        float mu1 = fminf(fmaxf(spy + DT * f1, SIGMA), 256.f - SIGMA);
        float sz0 = 0.5f - fabsf(px - mu0) + SIGMA;
        float sz1 = 0.5f - fabsf(py - mu1) + SIGMA;
        sz0 = fminf(fmaxf(sz0, 0.f), 1.f);
        sz1 = fminf(fmaxf(sz1, 0.f), 1.f);
        float area = sz0 * sz1 * INV4S2;
        float na = A[sb * NC + c] * area;
        nAc[c] = na;
        sumnA += na;
      }
      float e = __expf(sumnA) - 1.0f;
      accA[0] += nAc[0];
      accA[1] += nAc[1];
      accA[2] += nAc[2];
      esum += e;
      const float* pp = P + sb * NK;
#pragma unroll
      for (int k = 0; k < NK; ++k) accP[k] += pp[k] * e;
    }
  }
  const int b = x * 256 + y;
#pragma unroll
  for (int c = 0; c < NC; ++c) outA[b * NC + c] = accA[c];
  const float inv = 1.0f / (esum + 1e-10f);
#pragma unroll
  for (int k = 0; k < NK; ++k) outP[b * NK + k] = accP[k] * inv;
}

extern "C" void kernel_launch(void* const* d_in, const int* in_sizes, int n_in,
                              void* d_out, int out_size, void* d_ws, size_t ws_size,
                              hipStream_t stream) {
  const float* A   = (const float*)d_in[0];
  const float* P   = (const float*)d_in[1];
  const float* fKr = (const float*)d_in[2];
  const float* fKi = (const float*)d_in[3];
  const float* m   = (const float*)d_in[4];
  const float* s   = (const float*)d_in[5];

  float* ws = (float*)d_ws;
  float2* RF   = (float2*)ws;            // 3 * 65536 complex
  float2* T2   = RF + NC * XY;           // 15 * 65536 complex
  float*  Ucol = (float*)(T2 + NK * XY); // 3 * 65536 float
  float*  F    = Ucol + NC * XY;         // 65536 * 2 * 3 float

  float* outA = (float*)d_out;
  float* outP = outA + NC * XY;

  k_rowfft<<<NC * 256, 64, 0, stream>>>(A, RF);
  k_colfft<<<NK * 32, 512, 0, stream>>>(fKr, fKi, RF, T2);
  k_irowfft_growth<<<NC * 256, 320, 0, stream>>>(T2, P, m, s, Ucol);
  k_flow<<<256, 256, 0, stream>>>(A, Ucol, F);
  k_reint<<<256, 256, 0, stream>>>(A, P, F, outA, outP);
}